// Round 6
// baseline (357.314 us; speedup 1.0000x reference)
//
#include <hip/hip_runtime.h>
#include <hip/hip_bf16.h>

#define NPIX 16384
#define NVOC 8192
#define CHUNK 128

typedef short short8v __attribute__((ext_vector_type(8)));
typedef float floatx4 __attribute__((ext_vector_type(4)));

// ---- ws layout (bytes) ----
// region A (0..8 MB): zebf during cvt/gemm -> blist after gemm -> part tail
#define WS_ZEBF   0u          // 16384*256 bf16 = 8388608 (dead after k_gemm)
#define WS_BLIST  0u          // 128*16384 i32 = 8388608 (alias, post-gemm)
#define WS_PART   0u          // 256 f32 (alias, post-rescore; blist dead)
// region B: cbbf during gemm -> pk after gemm
#define WS_CBBF   8388608u    // 8192*256 bf16 = 4194304 (dead after k_gemm)
#define WS_PK     8388608u    // 16384 u64 = 131072 (alias, post-gemm)
// persistent
#define WS_ZEF    12582912u   // 16384*256 f32 = 16777216
#define WS_MIN    29360128u   // 128*16384 f32 = 8388608
#define WS_BN     37748736u   // 8192 f32
#define WS_AN     37781504u   // 16384 f32
#define WS_BCNT   37847040u   // 128 i32 (pad to 512)
#define WS_BMAXU  37847552u   // 1 u32 (pad)

__device__ __forceinline__ short f2bf(float v) {
  __bf16 h = (__bf16)v;
  return __builtin_bit_cast(short, h);
}

__device__ __forceinline__ float rl(float v, int l) {
  return __uint_as_float(__builtin_amdgcn_readlane(__float_as_uint(v), l));
}

__device__ __forceinline__ unsigned long long packdj(float d, int j) {
  return ((unsigned long long)__float_as_uint(d) << 32) | (unsigned int)j;
}

__device__ __forceinline__ void gll16(const void* g, void* l) {
  __builtin_amdgcn_global_load_lds(
      (const __attribute__((address_space(1))) void*)g,
      (__attribute__((address_space(3))) void*)l, 16, 0, 0);
}

// numpy pairwise-sum of 128 squares
__device__ __forceinline__ float np_pairwise128_sq(const float* x, int stride) {
  float r[8];
#pragma unroll
  for (int j = 0; j < 8; ++j) {
    float v = x[j * stride];
    r[j] = __fmul_rn(v, v);
  }
#pragma unroll
  for (int i = 1; i < 16; ++i) {
#pragma unroll
    for (int j = 0; j < 8; ++j) {
      float v = x[(i * 8 + j) * stride];
      r[j] = __fadd_rn(r[j], __fmul_rn(v, v));
    }
  }
  return __fadd_rn(__fadd_rn(__fadd_rn(r[0], r[1]), __fadd_rn(r[2], r[3])),
                   __fadd_rn(__fadd_rn(r[4], r[5]), __fadd_rn(r[6], r[7])));
}

// ||codebook_j||^2 (numpy order) + global max(bn) via atomicMax on bits
__global__ __launch_bounds__(256) void k_bnorm(const float* __restrict__ cb,
                                               float* __restrict__ bn,
                                               unsigned* __restrict__ bmaxu) {
  __shared__ float rows[64][257];
  int tid = threadIdx.x;
  int c0 = blockIdx.x * 64;
  for (int r = 0; r < 64; ++r)
    rows[r][tid] = cb[(size_t)(c0 + r) * 256 + tid];
  __syncthreads();
  if (tid < 64) {
    float a = np_pairwise128_sq(&rows[tid][0], 1);
    float b = np_pairwise128_sq(&rows[tid][128], 1);
    float v = __fadd_rn(a, b);
    bn[c0 + tid] = v;
    atomicMax(bmaxu, __float_as_uint(v));  // v >= 0: bit order == float order
  }
}

// ze [16][256][1024] fp32 -> zebf (bf16) + zef (fp32) [16384][256]; fused anorm
__global__ __launch_bounds__(256) void k_cvt_ze(const float* __restrict__ ze,
                                                short* __restrict__ zebf,
                                                float* __restrict__ zef,
                                                float* __restrict__ an) {
  __shared__ float t[64][132];
  int tid = threadIdx.x;
  int p0 = blockIdx.x * 64;
  int b = p0 >> 10, hw0 = p0 & 1023;
  const float* src = ze + (size_t)b * 262144 + hw0;
  float apart = 0.f;
  for (int half = 0; half < 2; ++half) {
    if (half) __syncthreads();
    {
      int hw = tid & 63, cq = tid >> 6;
#pragma unroll
      for (int i = 0; i < 32; ++i) {
        int cl = i * 4 + cq;
        t[hw][cl] = src[(size_t)(half * 128 + cl) * 1024 + hw];
      }
    }
    __syncthreads();
    int r = tid >> 2, cg = tid & 3;
    float* fd = zef + (size_t)(p0 + r) * 256 + half * 128 + cg * 32;
    short* bd = zebf + (size_t)(p0 + r) * 256 + half * 128 + cg * 32;
#pragma unroll
    for (int s = 0; s < 8; ++s) {
      float4 v = *reinterpret_cast<const float4*>(&t[r][cg * 32 + s * 4]);
      *reinterpret_cast<float4*>(fd + s * 4) = v;
    }
#pragma unroll
    for (int s = 0; s < 4; ++s) {
      short8v v8;
#pragma unroll
      for (int e = 0; e < 8; ++e) v8[e] = f2bf(t[r][cg * 32 + s * 8 + e]);
      *reinterpret_cast<short8v*>(bd + s * 8) = v8;
    }
    if (tid < 64) {
      float a = np_pairwise128_sq(&t[tid][0], 1);
      apart = half ? __fadd_rn(apart, a) : a;
    }
  }
  if (tid < 64) an[p0 + tid] = apart;
}

// cb -> bf16; also init bcnt/bmax (runs before k_bnorm/k_reduce)
__global__ __launch_bounds__(256) void k_cvt_cb(const float* __restrict__ cb,
                                                short* __restrict__ cbbf,
                                                unsigned* __restrict__ bmaxu,
                                                int* __restrict__ bcnt) {
  int tid = threadIdx.x;
  if (blockIdx.x == 0) {
    if (tid < 128) bcnt[tid] = 0;
    if (tid == 0) bmaxu[0] = 0u;
  }
  size_t i = ((size_t)blockIdx.x * 256 + tid) * 8;
  float4 a = *reinterpret_cast<const float4*>(cb + i);
  float4 b = *reinterpret_cast<const float4*>(cb + i + 4);
  short8v v;
  v[0] = f2bf(a.x); v[1] = f2bf(a.y); v[2] = f2bf(a.z); v[3] = f2bf(a.w);
  v[4] = f2bf(b.x); v[5] = f2bf(b.y); v[6] = f2bf(b.z); v[7] = f2bf(b.w);
  *reinterpret_cast<short8v*>(cbbf + i) = v;
}

// bf16 MFMA distance GEMM, 256x256 tile, 8 waves (2Mx4N), BK=64 dbuf,
// 8-phase schedule: global_load_lds staging (pre-swizzled source, linear LDS
// dest), counted vmcnt, per-phase barrier + lgkmcnt(0) + setprio MFMA cluster.
__global__ __launch_bounds__(512, 2) void k_gemm(const short* __restrict__ zebf,
                                                 const short* __restrict__ cbbf,
                                                 const float* __restrict__ bn,
                                                 float* __restrict__ wsmin) {
  __shared__ short As[2][16384];
  __shared__ short Bs[2][16384];
  int tid = threadIdx.x;
  int lane = tid & 63, w = tid >> 6;
  int wr = w >> 2, wc = w & 3;
  int g = lane >> 4, r16 = lane & 15;
  int swz = (blockIdx.x & 7) * 256 + (blockIdx.x >> 3);  // bijective, 2048%8==0
  int mb = swz & 63, nb = swz >> 6;
  int p0 = mb * 256, n0 = nb * 256;

  const short* Aq = zebf + (size_t)p0 * 256;
  const short* Bq = cbbf + (size_t)n0 * 256;

  floatx4 acc[8][4];
#pragma unroll
  for (int i = 0; i < 8; ++i)
#pragma unroll
    for (int j = 0; j < 4; ++j) acc[i][j] = floatx4{0.f, 0.f, 0.f, 0.f};

  // staging geometry: 1024 16B-chunks per half-tile; thread does chunks tid,
  // tid+512. LDS dest linear (chunk cid -> elem cid*8); global source column
  // pre-swizzled so the read-side XOR (c16 ^ row&7) sees logical data.
  int rl0 = tid >> 3, cs0 = ((tid & 7) ^ (rl0 & 7));
  int cid1 = tid + 512;
  int rl1 = cid1 >> 3, cs1 = ((cid1 & 7) ^ (rl1 & 7));

#define STAGE_HT(t, part)                                                      \
  {                                                                            \
    const short* sb_ = ((part) < 2) ? Aq : Bq;                                 \
    short* db_ = ((part) < 2) ? &As[(t)&1][0] : &Bs[(t)&1][0];                 \
    const int pr_ = ((part)&1) * 128;                                          \
    gll16(sb_ + (size_t)(pr_ + rl0) * 256 + (t) * 64 + cs0 * 8,                \
          db_ + pr_ * 64 + tid * 8);                                           \
    gll16(sb_ + (size_t)(pr_ + rl1) * 256 + (t) * 64 + cs1 * 8,                \
          db_ + pr_ * 64 + cid1 * 8);                                          \
  }

  short8v af[4];
  short8v bfv[2][4];

#define PHASE_PRE(t, rfh, ks)                                                  \
  {                                                                            \
    const int buf_ = (t)&1;                                                    \
    const int c16_ = (ks)*4 + g;                                               \
    _Pragma("unroll") for (int f = 0; f < 4; ++f) {                            \
      int row_ = wr * 128 + (rfh)*64 + f * 16 + r16;                           \
      af[f] = *reinterpret_cast<const short8v*>(                               \
          &As[buf_][row_ * 64 + ((c16_ ^ (row_ & 7)) * 8)]);                   \
    }                                                                          \
    if ((rfh) == 0) {                                                          \
      _Pragma("unroll") for (int cf = 0; cf < 4; ++cf) {                       \
        int col_ = wc * 64 + cf * 16 + r16;                                    \
        bfv[ks][cf] = *reinterpret_cast<const short8v*>(                       \
            &Bs[buf_][col_ * 64 + ((c16_ ^ (col_ & 7)) * 8)]);                 \
      }                                                                        \
    }                                                                          \
  }

#define PHASE_MMA(rfh, ks)                                                     \
  {                                                                            \
    __builtin_amdgcn_s_barrier();                                              \
    asm volatile("s_waitcnt lgkmcnt(0)" ::: "memory");                         \
    __builtin_amdgcn_sched_barrier(0);                                         \
    __builtin_amdgcn_s_setprio(1);                                             \
    _Pragma("unroll") for (int f = 0; f < 4; ++f)                              \
        _Pragma("unroll") for (int cf = 0; cf < 4; ++cf)                       \
            acc[(rfh)*4 + f][cf] = __builtin_amdgcn_mfma_f32_16x16x32_bf16(    \
                af[f], bfv[ks][cf], acc[(rfh)*4 + f][cf], 0, 0, 0);            \
    __builtin_amdgcn_s_setprio(0);                                             \
    __builtin_amdgcn_sched_barrier(0);                                         \
  }

#define BAR() __builtin_amdgcn_s_barrier();
#define VM0() asm volatile("s_waitcnt vmcnt(0)" ::: "memory");

  // prologue: stage tiles 0,1 (16 gll); wait tile0 (8 newest = tile1 in flight)
  STAGE_HT(0, 0) STAGE_HT(0, 1) STAGE_HT(0, 2) STAGE_HT(0, 3)
  STAGE_HT(1, 0) STAGE_HT(1, 1) STAGE_HT(1, 2) STAGE_HT(1, 3)
  asm volatile("s_waitcnt vmcnt(8)" ::: "memory");
  BAR()

  // tile0 (buf0)
  PHASE_PRE(0, 0, 0) PHASE_MMA(0, 0) BAR()
  PHASE_PRE(0, 0, 1) PHASE_MMA(0, 1) BAR()
  PHASE_PRE(0, 1, 0) PHASE_MMA(1, 0) BAR()
  PHASE_PRE(0, 1, 1) PHASE_MMA(1, 1) VM0() BAR()   // tile1 staged (prologue)
  // tile1 (buf1); stage tile2 into buf0 (tile0 reads done at last barrier)
  PHASE_PRE(1, 0, 0) STAGE_HT(2, 0) STAGE_HT(2, 1) PHASE_MMA(0, 0) BAR()
  PHASE_PRE(1, 0, 1) STAGE_HT(2, 2) STAGE_HT(2, 3) PHASE_MMA(0, 1) BAR()
  PHASE_PRE(1, 1, 0) PHASE_MMA(1, 0) BAR()
  PHASE_PRE(1, 1, 1) PHASE_MMA(1, 1) VM0() BAR()   // tile2 staged (>=2 phases old)
  // tile2 (buf0); stage tile3 into buf1 (tile1 reads done)
  PHASE_PRE(2, 0, 0) STAGE_HT(3, 0) STAGE_HT(3, 1) PHASE_MMA(0, 0) BAR()
  PHASE_PRE(2, 0, 1) STAGE_HT(3, 2) STAGE_HT(3, 3) PHASE_MMA(0, 1) BAR()
  PHASE_PRE(2, 1, 0) PHASE_MMA(1, 0) BAR()
  PHASE_PRE(2, 1, 1) PHASE_MMA(1, 1) VM0() BAR()   // tile3 staged
  // tile3 (buf1)
  PHASE_PRE(3, 0, 0) PHASE_MMA(0, 0) BAR()
  PHASE_PRE(3, 0, 1) PHASE_MMA(0, 1) BAR()
  PHASE_PRE(3, 1, 0) PHASE_MMA(1, 0) BAR()
  PHASE_PRE(3, 1, 1) PHASE_MMA(1, 1)

  // epilogue: t_hat = bn[j] - 2*dot ; per-pixel min over this wave's 64 cols
  float Bj[4];
#pragma unroll
  for (int cf = 0; cf < 4; ++cf) Bj[cf] = bn[n0 + wc * 64 + cf * 16 + r16];
  float* wout = wsmin + (size_t)(nb * 4 + wc) * NPIX + p0;
#pragma unroll
  for (int rf = 0; rf < 8; ++rf) {
    float rowmin[4];
#pragma unroll
    for (int rr = 0; rr < 4; ++rr) {
      float mv = 3.4e38f;
#pragma unroll
      for (int cf = 0; cf < 4; ++cf)
        mv = fminf(mv, __builtin_fmaf(-2.0f, acc[rf][cf][rr], Bj[cf]));
      rowmin[rr] = mv;
    }
#pragma unroll
    for (int off = 1; off < 16; off <<= 1)
#pragma unroll
      for (int rr = 0; rr < 4; ++rr)
        rowmin[rr] = fminf(rowmin[rr], __shfl_xor(rowmin[rr], off, 16));
    if (r16 == 0) {
#pragma unroll
      for (int rr = 0; rr < 4; ++rr)
        wout[wr * 128 + rf * 16 + g * 4 + rr] = rowmin[rr];
    }
  }
#undef STAGE_HT
#undef PHASE_PRE
#undef PHASE_MMA
#undef BAR
#undef VM0
}

// per-pixel tau; scatter flagged colblocks into buckets; init pk
__global__ __launch_bounds__(256) void k_reduce(const float* __restrict__ wsmin,
                                                const float* __restrict__ an,
                                                const unsigned* __restrict__ bmaxu,
                                                int* __restrict__ bcnt,
                                                int* __restrict__ blist,
                                                unsigned long long* __restrict__ pk) {
  int p = blockIdx.x * 256 + threadIdx.x;
  float mv = 3.4e38f;
#pragma unroll 8
  for (int c = 0; c < 128; ++c) mv = fminf(mv, wsmin[(size_t)c * NPIX + p]);
  float bmaxf = sqrtf(__uint_as_float(bmaxu[0]));
  float tp = mv + 0.017f * sqrtf(an[p]) * bmaxf + 2e-4f;
  pk[p] = ~0ull;
  for (int c = 0; c < 128; ++c) {
    if (wsmin[(size_t)c * NPIX + p] <= tp) {
      int slot = atomicAdd(&bcnt[c], 1);  // slot < NPIX always (<=1 per pixel)
      blist[(size_t)c * NPIX + slot] = p;
    }
  }
}

// bucketed exact fp32 rescore, persistent grid: 512 blocks stride over
// (chunk, colblock) combos; stage 64-code block once in LDS; waves process
// 4 pixels x 64 codes with readlane broadcast + serial k-ascending fmaf;
// lex-min (d, j) merged via 64-bit atomicMin (commutative -> deterministic).
__global__ __launch_bounds__(256) void k_rescore_b(
    const float* __restrict__ zef, const float* __restrict__ cb,
    const float* __restrict__ an, const float* __restrict__ bn,
    const int* __restrict__ bcnt, const int* __restrict__ blist,
    unsigned long long* __restrict__ pk) {
  __shared__ float cst[256][64];
  int tid = threadIdx.x;
  int lane = tid & 63, wv = tid >> 6;
  for (int id = blockIdx.x; id < 128 * 128; id += 512) {
    int c = id & 127;        // chunk-major: active ids clustered at low id
    int chunk = id >> 7;
    int n = bcnt[c];
    int base = chunk * CHUNK;
    if (base >= n) continue;  // block-uniform
    int cnt_here = min(CHUNK, n - base);
    __syncthreads();  // WAR vs previous combo's readers
    {
      int j = tid >> 2, kq = tid & 3;
      const float* src = cb + (size_t)(c * 64 + j) * 256 + kq * 64;
#pragma unroll
      for (int i = 0; i < 16; ++i) {
        float4 v = *reinterpret_cast<const float4*>(src + i * 4);
        int k = kq * 64 + i * 4;
        cst[k][j] = v.x; cst[k + 1][j] = v.y;
        cst[k + 2][j] = v.z; cst[k + 3][j] = v.w;
      }
    }
    __syncthreads();
    int j_global = c * 64 + lane;
    float bnj = bn[j_global];
    for (int g0 = wv * 4; g0 < cnt_here; g0 += 16) {
      int p[4];
      float4 z[4];
      float ap[4];
#pragma unroll
      for (int gi = 0; gi < 4; ++gi) {
        int idx = base + min(g0 + gi, cnt_here - 1);
        p[gi] = blist[(size_t)c * NPIX + idx];
        z[gi] = *reinterpret_cast<const float4*>(zef + (size_t)p[gi] * 256 +
                                                 lane * 4);
        ap[gi] = an[p[gi]];
      }
      float acc0 = 0.f, acc1 = 0.f, acc2 = 0.f, acc3 = 0.f;
#pragma unroll 8
      for (int k4 = 0; k4 < 64; ++k4) {
#pragma unroll
        for (int kk = 0; kk < 4; ++kk) {
          float cv = cst[k4 * 4 + kk][lane];
          float z0 = (kk == 0) ? z[0].x : (kk == 1) ? z[0].y : (kk == 2) ? z[0].z : z[0].w;
          float z1 = (kk == 0) ? z[1].x : (kk == 1) ? z[1].y : (kk == 2) ? z[1].z : z[1].w;
          float z2 = (kk == 0) ? z[2].x : (kk == 1) ? z[2].y : (kk == 2) ? z[2].z : z[2].w;
          float z3 = (kk == 0) ? z[3].x : (kk == 1) ? z[3].y : (kk == 2) ? z[3].z : z[3].w;
          acc0 = __builtin_fmaf(rl(z0, k4), cv, acc0);
          acc1 = __builtin_fmaf(rl(z1, k4), cv, acc1);
          acc2 = __builtin_fmaf(rl(z2, k4), cv, acc2);
          acc3 = __builtin_fmaf(rl(z3, k4), cv, acc3);
        }
      }
      float dv[4] = {acc0, acc1, acc2, acc3};
#pragma unroll
      for (int gi = 0; gi < 4; ++gi) {
        float d = __fsub_rn(__fadd_rn(ap[gi], bnj), 2.0f * dv[gi]);
        unsigned long long q = packdj(d, j_global);
#pragma unroll
        for (int off = 1; off < 64; off <<= 1) {
          unsigned long long q2 = __shfl_xor(q, off);
          q = q2 < q ? q2 : q;
        }
        if (lane == 0) atomicMin(&pk[p[gi]], q);
      }
    }
  }
}

__global__ __launch_bounds__(256) void k_gather(const float* __restrict__ ze,
                                                const float* __restrict__ cb,
                                                const unsigned long long* __restrict__ pk,
                                                float* __restrict__ out_zq,
                                                float* __restrict__ out_idx,
                                                float* __restrict__ part) {
  __shared__ float qrow[64][257];
  __shared__ int sidx[64];
  int tid = threadIdx.x;
  int p0 = blockIdx.x * 64;
  int b = p0 >> 10, hw0 = p0 & 1023;
  if (tid < 64) {
    int bi = (int)(unsigned int)(pk[p0 + tid] & 0xffffffffull);
    sidx[tid] = bi;
    out_idx[p0 + tid] = (float)bi;
  }
  __syncthreads();
  for (int r = 0; r < 64; ++r)
    qrow[r][tid] = cb[(size_t)sidx[r] * 256 + tid];
  __syncthreads();
  float lsum = 0.f;
  size_t zbase = (size_t)b * 262144 + hw0;
#pragma unroll 4
  for (int i = 0; i < 64; ++i) {
    int px = tid & 63;
    int c = i * 4 + (tid >> 6);
    float qv = qrow[px][c];
    size_t gi = zbase + (size_t)c * 1024 + px;
    float zev = ze[gi];
    out_zq[gi] = __fadd_rn(zev, __fsub_rn(qv, zev));
    float d = zev - qv;
    lsum = __builtin_fmaf(d, d, lsum);
  }
#pragma unroll
  for (int off = 32; off; off >>= 1) lsum += __shfl_xor(lsum, off, 64);
  __shared__ float wsum[4];
  if ((tid & 63) == 0) wsum[tid >> 6] = lsum;
  __syncthreads();
  if (tid == 0) part[blockIdx.x] = (wsum[0] + wsum[1]) + (wsum[2] + wsum[3]);
}

__global__ __launch_bounds__(256) void k_final(const float* __restrict__ part,
                                               float* __restrict__ out0) {
  int tid = threadIdx.x;
  float s = part[tid];
#pragma unroll
  for (int off = 32; off; off >>= 1) s += __shfl_xor(s, off, 64);
  __shared__ float wsum[4];
  if ((tid & 63) == 0) wsum[tid >> 6] = s;
  __syncthreads();
  if (tid == 0)
    out0[0] = 1.25f * ((wsum[0] + wsum[1]) + (wsum[2] + wsum[3])) / 4194304.0f;
}

extern "C" void kernel_launch(void* const* d_in, const int* in_sizes, int n_in,
                              void* d_out, int out_size, void* d_ws, size_t ws_size,
                              hipStream_t stream) {
  const float* ze = (const float*)d_in[0];
  const float* cb = (const float*)d_in[1];
  float* out = (float*)d_out;
  char* ws = (char*)d_ws;
  short* zebf = (short*)(ws + WS_ZEBF);
  short* cbbf = (short*)(ws + WS_CBBF);
  float* zef = (float*)(ws + WS_ZEF);
  float* bn = (float*)(ws + WS_BN);
  float* an = (float*)(ws + WS_AN);
  float* wsmin = (float*)(ws + WS_MIN);
  int* blist = (int*)(ws + WS_BLIST);
  int* bcnt = (int*)(ws + WS_BCNT);
  unsigned* bmaxu = (unsigned*)(ws + WS_BMAXU);
  unsigned long long* pk = (unsigned long long*)(ws + WS_PK);
  float* part = (float*)(ws + WS_PART);
  float* out_loss = out;
  float* out_zq = out + 1;
  float* out_idx = out + 1 + 4194304;

  k_cvt_ze<<<256, 256, 0, stream>>>(ze, zebf, zef, an);
  k_cvt_cb<<<1024, 256, 0, stream>>>(cb, cbbf, bmaxu, bcnt);
  k_bnorm<<<128, 256, 0, stream>>>(cb, bn, bmaxu);
  k_gemm<<<2048, 512, 0, stream>>>(zebf, cbbf, bn, wsmin);
  k_reduce<<<64, 256, 0, stream>>>(wsmin, an, bmaxu, bcnt, blist, pk);
  k_rescore_b<<<512, 256, 0, stream>>>(zef, cb, an, bn, bcnt, blist, pk);
  k_gather<<<256, 256, 0, stream>>>(ze, cb, pk, out_zq, out_idx, part);
  k_final<<<1, 256, 0, stream>>>(part, out_loss);
}

// Round 7
// 236.849 us; speedup vs baseline: 1.5086x; 1.5086x over previous
//
#include <hip/hip_runtime.h>
#include <hip/hip_bf16.h>

#define NPIX 16384
#define NVOC 8192
#define CHUNK 128

typedef short short8v __attribute__((ext_vector_type(8)));
typedef float floatx4 __attribute__((ext_vector_type(4)));

// ---- ws layout (bytes) ----
// region A (0..8 MB): zebf during cvt/gemm -> blist after gemm -> part tail
#define WS_ZEBF   0u          // 16384*256 bf16 = 8388608 (dead after k_gemm)
#define WS_BLIST  0u          // 128*16384 i32 = 8388608 (alias, post-gemm)
#define WS_PART   0u          // 256 f32 (alias, post-rescore; blist dead)
// region B: cbbf during gemm -> pk/tau after gemm
#define WS_CBBF   8388608u    // 8192*256 bf16 = 4194304 (dead after k_gemm)
#define WS_PK     8388608u    // 16384 u64 = 131072 (alias, post-gemm)
#define WS_TAU    8519680u    // 16384 f32 = 65536 (alias, post-gemm)
// persistent
#define WS_ZEF    12582912u   // 16384*256 f32 = 16777216
#define WS_MIN    29360128u   // 128*16384 f32 = 8388608
#define WS_BN     37748736u   // 8192 f32
#define WS_AN     37781504u   // 16384 f32
#define WS_BCNT   37847040u   // 128 i32 (pad to 512)
#define WS_BMAXU  37847552u   // 1 u32 (pad)

__device__ __forceinline__ short f2bf(float v) {
  __bf16 h = (__bf16)v;
  return __builtin_bit_cast(short, h);
}

__device__ __forceinline__ float rl(float v, int l) {
  return __uint_as_float(__builtin_amdgcn_readlane(__float_as_uint(v), l));
}

__device__ __forceinline__ unsigned long long packdj(float d, int j) {
  return ((unsigned long long)__float_as_uint(d) << 32) | (unsigned int)j;
}

__device__ __forceinline__ void gll16(const void* g, void* l) {
  __builtin_amdgcn_global_load_lds(
      (const __attribute__((address_space(1))) void*)g,
      (__attribute__((address_space(3))) void*)l, 16, 0, 0);
}

// numpy pairwise-sum of 128 squares
__device__ __forceinline__ float np_pairwise128_sq(const float* x, int stride) {
  float r[8];
#pragma unroll
  for (int j = 0; j < 8; ++j) {
    float v = x[j * stride];
    r[j] = __fmul_rn(v, v);
  }
#pragma unroll
  for (int i = 1; i < 16; ++i) {
#pragma unroll
    for (int j = 0; j < 8; ++j) {
      float v = x[(i * 8 + j) * stride];
      r[j] = __fadd_rn(r[j], __fmul_rn(v, v));
    }
  }
  return __fadd_rn(__fadd_rn(__fadd_rn(r[0], r[1]), __fadd_rn(r[2], r[3])),
                   __fadd_rn(__fadd_rn(r[4], r[5]), __fadd_rn(r[6], r[7])));
}

// ||codebook_j||^2 (numpy order) + global max(bn) via atomicMax on bits
__global__ __launch_bounds__(256) void k_bnorm(const float* __restrict__ cb,
                                               float* __restrict__ bn,
                                               unsigned* __restrict__ bmaxu) {
  __shared__ float rows[64][257];
  int tid = threadIdx.x;
  int c0 = blockIdx.x * 64;
  for (int r = 0; r < 64; ++r)
    rows[r][tid] = cb[(size_t)(c0 + r) * 256 + tid];
  __syncthreads();
  if (tid < 64) {
    float a = np_pairwise128_sq(&rows[tid][0], 1);
    float b = np_pairwise128_sq(&rows[tid][128], 1);
    float v = __fadd_rn(a, b);
    bn[c0 + tid] = v;
    atomicMax(bmaxu, __float_as_uint(v));  // v >= 0: bit order == float order
  }
}

// ze [16][256][1024] fp32 -> zebf (bf16) + zef (fp32) [16384][256]; fused anorm
__global__ __launch_bounds__(256) void k_cvt_ze(const float* __restrict__ ze,
                                                short* __restrict__ zebf,
                                                float* __restrict__ zef,
                                                float* __restrict__ an) {
  __shared__ float t[64][132];
  int tid = threadIdx.x;
  int p0 = blockIdx.x * 64;
  int b = p0 >> 10, hw0 = p0 & 1023;
  const float* src = ze + (size_t)b * 262144 + hw0;
  float apart = 0.f;
  for (int half = 0; half < 2; ++half) {
    if (half) __syncthreads();
    {
      int hw = tid & 63, cq = tid >> 6;
#pragma unroll
      for (int i = 0; i < 32; ++i) {
        int cl = i * 4 + cq;
        t[hw][cl] = src[(size_t)(half * 128 + cl) * 1024 + hw];
      }
    }
    __syncthreads();
    int r = tid >> 2, cg = tid & 3;
    float* fd = zef + (size_t)(p0 + r) * 256 + half * 128 + cg * 32;
    short* bd = zebf + (size_t)(p0 + r) * 256 + half * 128 + cg * 32;
#pragma unroll
    for (int s = 0; s < 8; ++s) {
      float4 v = *reinterpret_cast<const float4*>(&t[r][cg * 32 + s * 4]);
      *reinterpret_cast<float4*>(fd + s * 4) = v;
    }
#pragma unroll
    for (int s = 0; s < 4; ++s) {
      short8v v8;
#pragma unroll
      for (int e = 0; e < 8; ++e) v8[e] = f2bf(t[r][cg * 32 + s * 8 + e]);
      *reinterpret_cast<short8v*>(bd + s * 8) = v8;
    }
    if (tid < 64) {
      float a = np_pairwise128_sq(&t[tid][0], 1);
      apart = half ? __fadd_rn(apart, a) : a;
    }
  }
  if (tid < 64) an[p0 + tid] = apart;
}

// cb -> bf16; also init bmax
__global__ __launch_bounds__(256) void k_cvt_cb(const float* __restrict__ cb,
                                                short* __restrict__ cbbf,
                                                unsigned* __restrict__ bmaxu) {
  int tid = threadIdx.x;
  if (blockIdx.x == 0 && tid == 0) bmaxu[0] = 0u;
  size_t i = ((size_t)blockIdx.x * 256 + tid) * 8;
  float4 a = *reinterpret_cast<const float4*>(cb + i);
  float4 b = *reinterpret_cast<const float4*>(cb + i + 4);
  short8v v;
  v[0] = f2bf(a.x); v[1] = f2bf(a.y); v[2] = f2bf(a.z); v[3] = f2bf(a.w);
  v[4] = f2bf(b.x); v[5] = f2bf(b.y); v[6] = f2bf(b.z); v[7] = f2bf(b.w);
  *reinterpret_cast<short8v*>(cbbf + i) = v;
}

// bf16 MFMA distance GEMM, 256x256 tile, 8 waves (2Mx4N), BK=64 dbuf,
// 8-phase schedule: global_load_lds staging (pre-swizzled source, linear LDS
// dest), counted vmcnt, per-phase barrier + lgkmcnt(0) + setprio MFMA cluster.
__global__ __launch_bounds__(512, 2) void k_gemm(const short* __restrict__ zebf,
                                                 const short* __restrict__ cbbf,
                                                 const float* __restrict__ bn,
                                                 float* __restrict__ wsmin) {
  __shared__ short As[2][16384];
  __shared__ short Bs[2][16384];
  int tid = threadIdx.x;
  int lane = tid & 63, w = tid >> 6;
  int wr = w >> 2, wc = w & 3;
  int g = lane >> 4, r16 = lane & 15;
  int swz = (blockIdx.x & 7) * 256 + (blockIdx.x >> 3);  // bijective, 2048%8==0
  int mb = swz & 63, nb = swz >> 6;
  int p0 = mb * 256, n0 = nb * 256;

  const short* Aq = zebf + (size_t)p0 * 256;
  const short* Bq = cbbf + (size_t)n0 * 256;

  floatx4 acc[8][4];
#pragma unroll
  for (int i = 0; i < 8; ++i)
#pragma unroll
    for (int j = 0; j < 4; ++j) acc[i][j] = floatx4{0.f, 0.f, 0.f, 0.f};

  int rl0 = tid >> 3, cs0 = ((tid & 7) ^ (rl0 & 7));
  int cid1 = tid + 512;
  int rl1 = cid1 >> 3, cs1 = ((cid1 & 7) ^ (rl1 & 7));

#define STAGE_HT(t, part)                                                      \
  {                                                                            \
    const short* sb_ = ((part) < 2) ? Aq : Bq;                                 \
    short* db_ = ((part) < 2) ? &As[(t)&1][0] : &Bs[(t)&1][0];                 \
    const int pr_ = ((part)&1) * 128;                                          \
    gll16(sb_ + (size_t)(pr_ + rl0) * 256 + (t) * 64 + cs0 * 8,                \
          db_ + pr_ * 64 + tid * 8);                                           \
    gll16(sb_ + (size_t)(pr_ + rl1) * 256 + (t) * 64 + cs1 * 8,                \
          db_ + pr_ * 64 + cid1 * 8);                                          \
  }

  short8v af[4];
  short8v bfv[2][4];

#define PHASE_PRE(t, rfh, ks)                                                  \
  {                                                                            \
    const int buf_ = (t)&1;                                                    \
    const int c16_ = (ks)*4 + g;                                               \
    _Pragma("unroll") for (int f = 0; f < 4; ++f) {                            \
      int row_ = wr * 128 + (rfh)*64 + f * 16 + r16;                           \
      af[f] = *reinterpret_cast<const short8v*>(                               \
          &As[buf_][row_ * 64 + ((c16_ ^ (row_ & 7)) * 8)]);                   \
    }                                                                          \
    if ((rfh) == 0) {                                                          \
      _Pragma("unroll") for (int cf = 0; cf < 4; ++cf) {                       \
        int col_ = wc * 64 + cf * 16 + r16;                                    \
        bfv[ks][cf] = *reinterpret_cast<const short8v*>(                       \
            &Bs[buf_][col_ * 64 + ((c16_ ^ (col_ & 7)) * 8)]);                 \
      }                                                                        \
    }                                                                          \
  }

#define PHASE_MMA(rfh, ks)                                                     \
  {                                                                            \
    __builtin_amdgcn_s_barrier();                                              \
    asm volatile("s_waitcnt lgkmcnt(0)" ::: "memory");                         \
    __builtin_amdgcn_sched_barrier(0);                                         \
    __builtin_amdgcn_s_setprio(1);                                             \
    _Pragma("unroll") for (int f = 0; f < 4; ++f)                              \
        _Pragma("unroll") for (int cf = 0; cf < 4; ++cf)                       \
            acc[(rfh)*4 + f][cf] = __builtin_amdgcn_mfma_f32_16x16x32_bf16(    \
                af[f], bfv[ks][cf], acc[(rfh)*4 + f][cf], 0, 0, 0);            \
    __builtin_amdgcn_s_setprio(0);                                             \
    __builtin_amdgcn_sched_barrier(0);                                         \
  }

#define BAR() __builtin_amdgcn_s_barrier();
#define VM0() asm volatile("s_waitcnt vmcnt(0)" ::: "memory");

  STAGE_HT(0, 0) STAGE_HT(0, 1) STAGE_HT(0, 2) STAGE_HT(0, 3)
  STAGE_HT(1, 0) STAGE_HT(1, 1) STAGE_HT(1, 2) STAGE_HT(1, 3)
  asm volatile("s_waitcnt vmcnt(8)" ::: "memory");
  BAR()

  PHASE_PRE(0, 0, 0) PHASE_MMA(0, 0) BAR()
  PHASE_PRE(0, 0, 1) PHASE_MMA(0, 1) BAR()
  PHASE_PRE(0, 1, 0) PHASE_MMA(1, 0) BAR()
  PHASE_PRE(0, 1, 1) PHASE_MMA(1, 1) VM0() BAR()
  PHASE_PRE(1, 0, 0) STAGE_HT(2, 0) STAGE_HT(2, 1) PHASE_MMA(0, 0) BAR()
  PHASE_PRE(1, 0, 1) STAGE_HT(2, 2) STAGE_HT(2, 3) PHASE_MMA(0, 1) BAR()
  PHASE_PRE(1, 1, 0) PHASE_MMA(1, 0) BAR()
  PHASE_PRE(1, 1, 1) PHASE_MMA(1, 1) VM0() BAR()
  PHASE_PRE(2, 0, 0) STAGE_HT(3, 0) STAGE_HT(3, 1) PHASE_MMA(0, 0) BAR()
  PHASE_PRE(2, 0, 1) STAGE_HT(3, 2) STAGE_HT(3, 3) PHASE_MMA(0, 1) BAR()
  PHASE_PRE(2, 1, 0) PHASE_MMA(1, 0) BAR()
  PHASE_PRE(2, 1, 1) PHASE_MMA(1, 1) VM0() BAR()
  PHASE_PRE(3, 0, 0) PHASE_MMA(0, 0) BAR()
  PHASE_PRE(3, 0, 1) PHASE_MMA(0, 1) BAR()
  PHASE_PRE(3, 1, 0) PHASE_MMA(1, 0) BAR()
  PHASE_PRE(3, 1, 1) PHASE_MMA(1, 1)

  float Bj[4];
#pragma unroll
  for (int cf = 0; cf < 4; ++cf) Bj[cf] = bn[n0 + wc * 64 + cf * 16 + r16];
  float* wout = wsmin + (size_t)(nb * 4 + wc) * NPIX + p0;
#pragma unroll
  for (int rf = 0; rf < 8; ++rf) {
    float rowmin[4];
#pragma unroll
    for (int rr = 0; rr < 4; ++rr) {
      float mv = 3.4e38f;
#pragma unroll
      for (int cf = 0; cf < 4; ++cf)
        mv = fminf(mv, __builtin_fmaf(-2.0f, acc[rf][cf][rr], Bj[cf]));
      rowmin[rr] = mv;
    }
#pragma unroll
    for (int off = 1; off < 16; off <<= 1)
#pragma unroll
      for (int rr = 0; rr < 4; ++rr)
        rowmin[rr] = fminf(rowmin[rr], __shfl_xor(rowmin[rr], off, 16));
    if (r16 == 0) {
#pragma unroll
      for (int rr = 0; rr < 4; ++rr)
        wout[wr * 128 + rf * 16 + g * 4 + rr] = rowmin[rr];
    }
  }
#undef STAGE_HT
#undef PHASE_PRE
#undef PHASE_MMA
#undef BAR
#undef VM0
}

// per-pixel global min over 128 colblocks -> tau; init pk. No atomics.
// 256 blocks x 64 pixels; 4 waves each take a 32-colblock quarter.
__global__ __launch_bounds__(256) void k_tau(const float* __restrict__ wsmin,
                                             const float* __restrict__ an,
                                             const unsigned* __restrict__ bmaxu,
                                             float* __restrict__ tau,
                                             unsigned long long* __restrict__ pk) {
  __shared__ float sm[4][64];
  int tid = threadIdx.x;
  int px = tid & 63, q = tid >> 6;
  int p = blockIdx.x * 64 + px;
  float m0 = 3.4e38f, m1 = 3.4e38f, m2 = 3.4e38f, m3 = 3.4e38f;
#pragma unroll
  for (int i = 0; i < 8; ++i) {
    int c = q * 32 + i * 4;
    m0 = fminf(m0, wsmin[(size_t)c * NPIX + p]);
    m1 = fminf(m1, wsmin[(size_t)(c + 1) * NPIX + p]);
    m2 = fminf(m2, wsmin[(size_t)(c + 2) * NPIX + p]);
    m3 = fminf(m3, wsmin[(size_t)(c + 3) * NPIX + p]);
  }
  sm[q][px] = fminf(fminf(m0, m1), fminf(m2, m3));
  __syncthreads();
  if (tid < 64) {
    float m = fminf(fminf(sm[0][tid], sm[1][tid]), fminf(sm[2][tid], sm[3][tid]));
    float bmaxf = sqrtf(__uint_as_float(bmaxu[0]));
    tau[p] = m + 0.017f * sqrtf(an[p]) * bmaxf + 2e-4f;
    pk[p] = ~0ull;
  }
}

// per-colblock compaction of flagged pixels, ascending p, zero atomics.
// One block per colblock c; ballot + popcount prefix scan.
__global__ __launch_bounds__(256) void k_compact(const float* __restrict__ wsmin,
                                                 const float* __restrict__ tau,
                                                 int* __restrict__ bcnt,
                                                 int* __restrict__ blist) {
  __shared__ int wbase[4];
  __shared__ int running;
  int c = blockIdx.x;
  const float* row = wsmin + (size_t)c * NPIX;
  int* dst = blist + (size_t)c * NPIX;
  int tid = threadIdx.x;
  int lane = tid & 63, wv = tid >> 6;
  if (tid == 0) running = 0;
  __syncthreads();
  for (int base = 0; base < NPIX; base += 256) {
    int p = base + tid;
    bool flag = row[p] <= tau[p];
    unsigned long long mask = __ballot(flag);
    int cnt = __popcll(mask);
    int pre = __popcll(mask & ((1ull << lane) - 1ull));
    if (lane == 0) wbase[wv] = cnt;
    __syncthreads();
    if (tid == 0) {
      int r = running;
#pragma unroll
      for (int w2 = 0; w2 < 4; ++w2) {
        int t = wbase[w2];
        wbase[w2] = r;
        r += t;
      }
      running = r;
    }
    __syncthreads();
    if (flag) dst[wbase[wv] + pre] = p;
    __syncthreads();
  }
  if (tid == 0) bcnt[c] = running;
}

// bucketed exact fp32 rescore, persistent grid.
__global__ __launch_bounds__(256) void k_rescore_b(
    const float* __restrict__ zef, const float* __restrict__ cb,
    const float* __restrict__ an, const float* __restrict__ bn,
    const int* __restrict__ bcnt, const int* __restrict__ blist,
    unsigned long long* __restrict__ pk) {
  __shared__ float cst[256][64];
  int tid = threadIdx.x;
  int lane = tid & 63, wv = tid >> 6;
  for (int id = blockIdx.x; id < 128 * 128; id += 512) {
    int c = id & 127;
    int chunk = id >> 7;
    int n = bcnt[c];
    int base = chunk * CHUNK;
    if (base >= n) continue;
    int cnt_here = min(CHUNK, n - base);
    __syncthreads();
    {
      int j = tid >> 2, kq = tid & 3;
      const float* src = cb + (size_t)(c * 64 + j) * 256 + kq * 64;
#pragma unroll
      for (int i = 0; i < 16; ++i) {
        float4 v = *reinterpret_cast<const float4*>(src + i * 4);
        int k = kq * 64 + i * 4;
        cst[k][j] = v.x; cst[k + 1][j] = v.y;
        cst[k + 2][j] = v.z; cst[k + 3][j] = v.w;
      }
    }
    __syncthreads();
    int j_global = c * 64 + lane;
    float bnj = bn[j_global];
    for (int g0 = wv * 4; g0 < cnt_here; g0 += 16) {
      int p[4];
      float4 z[4];
      float ap[4];
#pragma unroll
      for (int gi = 0; gi < 4; ++gi) {
        int idx = base + min(g0 + gi, cnt_here - 1);
        p[gi] = blist[(size_t)c * NPIX + idx];
        z[gi] = *reinterpret_cast<const float4*>(zef + (size_t)p[gi] * 256 +
                                                 lane * 4);
        ap[gi] = an[p[gi]];
      }
      float acc0 = 0.f, acc1 = 0.f, acc2 = 0.f, acc3 = 0.f;
#pragma unroll 8
      for (int k4 = 0; k4 < 64; ++k4) {
#pragma unroll
        for (int kk = 0; kk < 4; ++kk) {
          float cv = cst[k4 * 4 + kk][lane];
          float z0 = (kk == 0) ? z[0].x : (kk == 1) ? z[0].y : (kk == 2) ? z[0].z : z[0].w;
          float z1 = (kk == 0) ? z[1].x : (kk == 1) ? z[1].y : (kk == 2) ? z[1].z : z[1].w;
          float z2 = (kk == 0) ? z[2].x : (kk == 1) ? z[2].y : (kk == 2) ? z[2].z : z[2].w;
          float z3 = (kk == 0) ? z[3].x : (kk == 1) ? z[3].y : (kk == 2) ? z[3].z : z[3].w;
          acc0 = __builtin_fmaf(rl(z0, k4), cv, acc0);
          acc1 = __builtin_fmaf(rl(z1, k4), cv, acc1);
          acc2 = __builtin_fmaf(rl(z2, k4), cv, acc2);
          acc3 = __builtin_fmaf(rl(z3, k4), cv, acc3);
        }
      }
      float dv[4] = {acc0, acc1, acc2, acc3};
#pragma unroll
      for (int gi = 0; gi < 4; ++gi) {
        float d = __fsub_rn(__fadd_rn(ap[gi], bnj), 2.0f * dv[gi]);
        unsigned long long q = packdj(d, j_global);
#pragma unroll
        for (int off = 1; off < 64; off <<= 1) {
          unsigned long long q2 = __shfl_xor(q, off);
          q = q2 < q ? q2 : q;
        }
        if (lane == 0) atomicMin(&pk[p[gi]], q);
      }
    }
  }
}

__global__ __launch_bounds__(256) void k_gather(const float* __restrict__ ze,
                                                const float* __restrict__ cb,
                                                const unsigned long long* __restrict__ pk,
                                                float* __restrict__ out_zq,
                                                float* __restrict__ out_idx,
                                                float* __restrict__ part) {
  __shared__ float qrow[64][257];
  __shared__ int sidx[64];
  int tid = threadIdx.x;
  int p0 = blockIdx.x * 64;
  int b = p0 >> 10, hw0 = p0 & 1023;
  if (tid < 64) {
    int bi = (int)(unsigned int)(pk[p0 + tid] & 0xffffffffull);
    sidx[tid] = bi;
    out_idx[p0 + tid] = (float)bi;
  }
  __syncthreads();
  for (int r = 0; r < 64; ++r)
    qrow[r][tid] = cb[(size_t)sidx[r] * 256 + tid];
  __syncthreads();
  float lsum = 0.f;
  size_t zbase = (size_t)b * 262144 + hw0;
#pragma unroll 4
  for (int i = 0; i < 64; ++i) {
    int px = tid & 63;
    int c = i * 4 + (tid >> 6);
    float qv = qrow[px][c];
    size_t gi = zbase + (size_t)c * 1024 + px;
    float zev = ze[gi];
    out_zq[gi] = __fadd_rn(zev, __fsub_rn(qv, zev));
    float d = zev - qv;
    lsum = __builtin_fmaf(d, d, lsum);
  }
#pragma unroll
  for (int off = 32; off; off >>= 1) lsum += __shfl_xor(lsum, off, 64);
  __shared__ float wsum[4];
  if ((tid & 63) == 0) wsum[tid >> 6] = lsum;
  __syncthreads();
  if (tid == 0) part[blockIdx.x] = (wsum[0] + wsum[1]) + (wsum[2] + wsum[3]);
}

__global__ __launch_bounds__(256) void k_final(const float* __restrict__ part,
                                               float* __restrict__ out0) {
  int tid = threadIdx.x;
  float s = part[tid];
#pragma unroll
  for (int off = 32; off; off >>= 1) s += __shfl_xor(s, off, 64);
  __shared__ float wsum[4];
  if ((tid & 63) == 0) wsum[tid >> 6] = s;
  __syncthreads();
  if (tid == 0)
    out0[0] = 1.25f * ((wsum[0] + wsum[1]) + (wsum[2] + wsum[3])) / 4194304.0f;
}

extern "C" void kernel_launch(void* const* d_in, const int* in_sizes, int n_in,
                              void* d_out, int out_size, void* d_ws, size_t ws_size,
                              hipStream_t stream) {
  const float* ze = (const float*)d_in[0];
  const float* cb = (const float*)d_in[1];
  float* out = (float*)d_out;
  char* ws = (char*)d_ws;
  short* zebf = (short*)(ws + WS_ZEBF);
  short* cbbf = (short*)(ws + WS_CBBF);
  float* zef = (float*)(ws + WS_ZEF);
  float* bn = (float*)(ws + WS_BN);
  float* an = (float*)(ws + WS_AN);
  float* wsmin = (float*)(ws + WS_MIN);
  float* tau = (float*)(ws + WS_TAU);
  int* blist = (int*)(ws + WS_BLIST);
  int* bcnt = (int*)(ws + WS_BCNT);
  unsigned* bmaxu = (unsigned*)(ws + WS_BMAXU);
  unsigned long long* pk = (unsigned long long*)(ws + WS_PK);
  float* part = (float*)(ws + WS_PART);
  float* out_loss = out;
  float* out_zq = out + 1;
  float* out_idx = out + 1 + 4194304;

  k_cvt_ze<<<256, 256, 0, stream>>>(ze, zebf, zef, an);
  k_cvt_cb<<<1024, 256, 0, stream>>>(cb, cbbf, bmaxu);
  k_bnorm<<<128, 256, 0, stream>>>(cb, bn, bmaxu);
  k_gemm<<<2048, 512, 0, stream>>>(zebf, cbbf, bn, wsmin);
  k_tau<<<256, 256, 0, stream>>>(wsmin, an, bmaxu, tau, pk);
  k_compact<<<128, 256, 0, stream>>>(wsmin, tau, bcnt, blist);
  k_rescore_b<<<512, 256, 0, stream>>>(zef, cb, an, bn, bcnt, blist, pk);
  k_gather<<<256, 256, 0, stream>>>(ze, cb, pk, out_zq, out_idx, part);
  k_final<<<1, 256, 0, stream>>>(part, out_loss);
}